// Round 5
// baseline (171.458 us; speedup 1.0000x reference)
//
#include <hip/hip_runtime.h>
#include <hip/hip_bf16.h>
#include <math.h>

#define LEAKY 0.01f
#define B_    2048
#define F_    512
#define H_    64
#define K_    8
#define D_    128
#define ASR_  128
#define MM_   768
#define OUT_  256
#define PROJ_IN 66432          // 128+768+512*128
#define ZK    4992             // 896 + 512*8 (emb folded into proj_w)
#define PK    4096             // F_*K_
#define NSPLIT 8               // gemm split-K factor

// ---------------- workspace layout (bytes) ----------------
// P    : [B_][PK]   bf16        @ 0           16,777,216
// Wn   : [OUT_][ZK] bf16        @ 16,777,216   2,555,904
// part : [8][B_][OUT_] fp32     @ 19,333,120  16,777,216
// total 36,110,336  (actual ws_size ~272 MB per poison WRITE_SIZE)

typedef unsigned short u16;
typedef u16   u16x4 __attribute__((ext_vector_type(4)));
typedef u16   u16x8 __attribute__((ext_vector_type(8)));
typedef short s16x8 __attribute__((ext_vector_type(8)));
typedef float f32x4 __attribute__((ext_vector_type(4)));

__device__ __forceinline__ u16 f2bf(float x) {   // RNE float->bf16 bits
  unsigned int u = __float_as_uint(x);
  u += 0x7fffu + ((u >> 16) & 1u);
  return (u16)(u >> 16);
}

// ---------------------------------------------------------------------------
// Fused producers. Heterogeneous blocks:
//   bid < 1024        : probs tile  (4 features x 256 rows)  [R4: 8 feat -> acc[8][8]
//                       spilled at VGPR=68; 4 feat -> acc[4][8]=32 regs, no spill]
//   1024 <= bid <3072 : wn_g item   (feature f, 64 o-rows)
//   3072 <= bid <3296 : wn_top slab (1024 elements)
#define W1S 65
#define W2S 516
#define PRODUCER_BLOCKS (1024 + 2048 + 224)

__global__ __launch_bounds__(256) void producer_kernel(
    const float* __restrict__ stat, const float* __restrict__ w1,
    const float* __restrict__ b1v, const float* __restrict__ w2,
    const float* __restrict__ b2v, const float* __restrict__ tauv,
    const float* __restrict__ pw, const float* __restrict__ emb,
    u16* __restrict__ P, u16* __restrict__ Wn) {
  __shared__ __align__(16) char smem[14688];
  const int bid = blockIdx.x;
  const int t = threadIdx.x;

  if (bid < 1024) {
    // ---------------- probs: 4 features x 256 rows ----------------
    const int f0 = (bid & 127) * 4;
    const int b0 = (bid >> 7) * 256;
    float* s_w1s = (float*)(smem);                    // 4*65 = 1040 B
    float* s_b1  = (float*)(smem + 1040);             // 1040 B
    float* s_w2  = (float*)(smem + 2080);             // 4*516*4 = 8256 B (16B aligned)
    float* s_b2  = (float*)(smem + 10336);            // 128 B
    float* s_tau = (float*)(smem + 10464);            // 128 B
    float* s_x   = (float*)(smem + 10592);            // 256*4*4 = 4096 B
    {
      int fl = t >> 6, h = t & 63;                    // 256 thr = 4 feat x 64 h
      const float* wf = w1 + (size_t)(f0 + fl) * 192;
      s_w1s[fl * W1S + h] = wf[h] + wf[64 + h] + wf[128 + h];  // 3 copies of x
      s_b1[fl * W1S + h] = b1v[(size_t)(f0 + fl) * 64 + h];
    }
    for (int i = t; i < 4 * 512; i += 256) {
      int fl = i >> 9, idx = i & 511;
      s_w2[fl * W2S + idx] = w2[(size_t)(f0 + fl) * 512 + idx];
    }
    if (t < 32) {
      int fl = t >> 3, k = t & 7;
      s_b2[t]  = b2v[(f0 + fl) * 8 + k];
      s_tau[t] = tauv[(f0 + fl) * 8 + k];
    }
    for (int i = t; i < 1024; i += 256) {             // coalesced stat tile
      int r = i >> 2, j = i & 3;
      float v = stat[(size_t)(b0 + r) * F_ + f0 + j];
      s_x[i] = (v >= 0.f) ? v : 0.f;                  // NaN -> 0, neg -> 0
    }
    __syncthreads();

    const int fl = t & 3, rb = t >> 2;                // 4 rows/thread: rb+64p
    float x[4];
    #pragma unroll
    for (int p = 0; p < 4; ++p) x[p] = s_x[(rb + 64 * p) * 4 + fl];
    float acc[4][8] = {{0.f}};
    const float* w1p = s_w1s + fl * W1S;
    const float* b1p = s_b1 + fl * W1S;
    const float* w2p = s_w2 + fl * W2S;
    #pragma unroll 8
    for (int i = 0; i < 64; ++i) {
      float wv = w1p[i], bv = b1p[i];
      float4 wa = *(const float4*)(w2p + i * 8);
      float4 wb = *(const float4*)(w2p + i * 8 + 4);
      #pragma unroll
      for (int p = 0; p < 4; ++p) {
        float h = fmaf(x[p], wv, bv);
        h = (h >= 0.f) ? h : LEAKY * h;
        acc[p][0] = fmaf(h, wa.x, acc[p][0]);
        acc[p][1] = fmaf(h, wa.y, acc[p][1]);
        acc[p][2] = fmaf(h, wa.z, acc[p][2]);
        acc[p][3] = fmaf(h, wa.w, acc[p][3]);
        acc[p][4] = fmaf(h, wb.x, acc[p][4]);
        acc[p][5] = fmaf(h, wb.y, acc[p][5]);
        acc[p][6] = fmaf(h, wb.z, acc[p][6]);
        acc[p][7] = fmaf(h, wb.w, acc[p][7]);
      }
    }
    #pragma unroll
    for (int p = 0; p < 4; ++p) {
      float s[K_];
      float m = -1e30f;
      #pragma unroll
      for (int k = 0; k < K_; ++k) {
        float v = acc[p][k] + s_b2[fl * 8 + k];
        v = (v >= 0.f) ? v : LEAKY * v;
        v *= s_tau[fl * 8 + k];
        s[k] = v;
        m = fmaxf(m, v);
      }
      float sum = 0.f;
      #pragma unroll
      for (int k = 0; k < K_; ++k) { s[k] = __expf(s[k] - m); sum += s[k]; }
      float inv = 1.f / sum;
      u16x8 hv;
      #pragma unroll
      for (int k = 0; k < K_; ++k) hv[k] = f2bf(s[k] * inv);
      *(u16x8*)(P + (size_t)(b0 + rb + 64 * p) * PK + (f0 + fl) * 8) = hv;
    }
  } else if (bid < 3072) {
    // ---------------- wn_g: Wn[o][896+f*8+k] = sum_d emb[f,k,d]*pw[o,896+f*128+d]
    const int item = bid - 1024;
    const int f = item >> 2;
    const int o0 = (item & 3) * 64;
    float* s_emb = (float*)smem;                      // 4 KB
    for (int i = t; i < K_ * D_; i += 256) s_emb[i] = emb[(size_t)f * K_ * D_ + i];
    __syncthreads();
    const int orow = t >> 2, dc = t & 3;              // quad reads 64B contiguous
    const float* src = pw + (size_t)(o0 + orow) * PROJ_IN + 896 + f * D_;
    float g[K_] = {0.f, 0.f, 0.f, 0.f, 0.f, 0.f, 0.f, 0.f};
    #pragma unroll
    for (int j = 0; j < 8; ++j) {
      const int d = dc * 4 + j * 16;
      float4 w = *(const float4*)(src + d);
      #pragma unroll
      for (int k = 0; k < K_; ++k) {
        float4 e = *(const float4*)(s_emb + k * D_ + d);
        g[k] = fmaf(w.x, e.x, g[k]);
        g[k] = fmaf(w.y, e.y, g[k]);
        g[k] = fmaf(w.z, e.z, g[k]);
        g[k] = fmaf(w.w, e.w, g[k]);
      }
    }
    #pragma unroll
    for (int k = 0; k < K_; ++k) {
      g[k] += __shfl_xor(g[k], 1);
      g[k] += __shfl_xor(g[k], 2);
    }
    if (dc == 0) {
      u16x8 hv;
      #pragma unroll
      for (int k = 0; k < K_; ++k) hv[k] = f2bf(g[k]);
      *(u16x8*)(Wn + (size_t)(o0 + orow) * ZK + 896 + f * K_) = hv;
    }
  } else {
    // ---------------- wn_top: Wn[o][j] = bf16(pw[o][j]), j<896
    const int item = bid - 3072;                      // 224 blocks x 1024 elems
    #pragma unroll
    for (int r = 0; r < 4; ++r) {
      int idx = item * 1024 + r * 256 + t;            // coalesced
      int o = idx / 896, j = idx % 896;
      Wn[(size_t)o * ZK + j] = f2bf(pw[(size_t)o * PROJ_IN + j]);
    }
  }
}

// ---------------------------------------------------------------------------
// MFMA GEMM, split-K=8: part[kz][b][o] = sum_{k slice} A[b][k]*Wn[o][k]
// BM=64 BN=64 BK=128; grid (32,4,8)=1024 blocks (4/CU, LDS-bound).
// Cache traffic: A x4 + Wn x32 = 176 MB (R4 tiles were 352 MB).
#define SAS 136   // u16 row stride: 272 B = 17*16 (2-way bank groups, free)
__global__ __launch_bounds__(256) void gemm_kernel(
    const float* __restrict__ asr, const float* __restrict__ mm,
    const u16* __restrict__ P, const u16* __restrict__ Wn,
    float* __restrict__ part) {
  const int bm0 = blockIdx.x * 64;
  const int bn0 = blockIdx.y * 64;
  const int kz  = blockIdx.z;
  const int it0 = kz * 5;
  const int itn = (kz == 7) ? 4 : 5;                  // 7*5+4 = 39 iters
  __shared__ u16 sA[64 * SAS];                        // 17408 B
  __shared__ u16 sB[64 * SAS];                        // 17408 B
  const int t = threadIdx.x;
  const int w = t >> 6, L = t & 63;
  const int l16 = L & 15, q8 = (L >> 4) * 8;
  const int wm = (w >> 1) * 32, wn = (w & 1) * 32;    // 2x2 wave grid
  const int row = t >> 2, lk = t & 3;                 // staging: 4 thr/row, 32 cols each
  f32x4 acc[2][2] = {{{0.f,0.f,0.f,0.f},{0.f,0.f,0.f,0.f}},
                     {{0.f,0.f,0.f,0.f},{0.f,0.f,0.f,0.f}}};
  float4 fa[8];       // prefetch: fp32 A iters
  u16x8 pa[4];        // prefetch: P iters
  u16x8 wb[4];        // prefetch: B

#define LOAD_TILES(IT)                                                        \
  {                                                                           \
    const int k0_ = (IT) * 128;                                               \
    if (k0_ == 0) {                                                           \
      const float* s_ = asr + (size_t)(bm0 + row) * ASR_ + lk * 32;           \
      _Pragma("unroll")                                                       \
      for (int j_ = 0; j_ < 8; ++j_) fa[j_] = *(const float4*)(s_ + j_ * 4);  \
    } else if (k0_ < 896) {                                                   \
      const float* s_ = mm + (size_t)(bm0 + row) * MM_ + (k0_ - 128) + lk * 32;\
      _Pragma("unroll")                                                       \
      for (int j_ = 0; j_ < 8; ++j_) fa[j_] = *(const float4*)(s_ + j_ * 4);  \
    } else {                                                                  \
      const u16* s_ = P + (size_t)(bm0 + row) * PK + (k0_ - 896) + lk * 32;   \
      _Pragma("unroll")                                                       \
      for (int j_ = 0; j_ < 4; ++j_) pa[j_] = *(const u16x8*)(s_ + j_ * 8);   \
    }                                                                         \
    const u16* sb_ = Wn + (size_t)(bn0 + row) * ZK + k0_ + lk * 32;           \
    _Pragma("unroll")                                                         \
    for (int j_ = 0; j_ < 4; ++j_) wb[j_] = *(const u16x8*)(sb_ + j_ * 8);    \
  }

#define STORE_TILES(IT)                                                       \
  {                                                                           \
    if ((IT) * 128 < 896) {                                                   \
      _Pragma("unroll")                                                       \
      for (int j_ = 0; j_ < 8; ++j_) {                                        \
        u16x4 h_ = {f2bf(fa[j_].x), f2bf(fa[j_].y), f2bf(fa[j_].z),           \
                    f2bf(fa[j_].w)};                                          \
        *(u16x4*)&sA[row * SAS + lk * 32 + j_ * 4] = h_;                      \
      }                                                                       \
    } else {                                                                  \
      _Pragma("unroll")                                                       \
      for (int j_ = 0; j_ < 4; ++j_)                                          \
        *(u16x8*)&sA[row * SAS + lk * 32 + j_ * 8] = pa[j_];                  \
    }                                                                         \
    _Pragma("unroll")                                                         \
    for (int j_ = 0; j_ < 4; ++j_)                                            \
      *(u16x8*)&sB[row * SAS + lk * 32 + j_ * 8] = wb[j_];                    \
  }

  LOAD_TILES(it0);
  for (int it = it0; it < it0 + itn; ++it) {
    __syncthreads();
    STORE_TILES(it);
    __syncthreads();
    if (it + 1 < it0 + itn) LOAD_TILES(it + 1);   // overlap next load with MFMA
    #pragma unroll
    for (int ks = 0; ks < 4; ++ks) {
      s16x8 a0 = *(const s16x8*)&sA[(wm + l16) * SAS + ks * 32 + q8];
      s16x8 a1 = *(const s16x8*)&sA[(wm + 16 + l16) * SAS + ks * 32 + q8];
      s16x8 b0 = *(const s16x8*)&sB[(wn + l16) * SAS + ks * 32 + q8];
      s16x8 b1 = *(const s16x8*)&sB[(wn + 16 + l16) * SAS + ks * 32 + q8];
      acc[0][0] = __builtin_amdgcn_mfma_f32_16x16x32_bf16(a0, b0, acc[0][0], 0, 0, 0);
      acc[0][1] = __builtin_amdgcn_mfma_f32_16x16x32_bf16(a0, b1, acc[0][1], 0, 0, 0);
      acc[1][0] = __builtin_amdgcn_mfma_f32_16x16x32_bf16(a1, b0, acc[1][0], 0, 0, 0);
      acc[1][1] = __builtin_amdgcn_mfma_f32_16x16x32_bf16(a1, b1, acc[1][1], 0, 0, 0);
    }
  }
#undef LOAD_TILES
#undef STORE_TILES

  float* dst = part + (size_t)kz * B_ * OUT_;
  #pragma unroll
  for (int mf = 0; mf < 2; ++mf) {
    const int r0 = bm0 + wm + mf * 16 + (L >> 4) * 4;   // C/D: col=lane&15, row=quad*4+i
    #pragma unroll
    for (int nf = 0; nf < 2; ++nf) {
      const int col = bn0 + wn + nf * 16 + l16;
      #pragma unroll
      for (int i = 0; i < 4; ++i)
        dst[(size_t)(r0 + i) * OUT_ + col] = acc[mf][nf][i];
    }
  }
}

// ---------------------------------------------------------------------------
// combine: out = relu(sum_kz part[kz] + bias), float4 per thread
__global__ __launch_bounds__(256) void combine_kernel(
    const float* __restrict__ part, const float* __restrict__ pb,
    float* __restrict__ out) {
  const int idx4 = (blockIdx.x * 256 + threadIdx.x) * 4;   // grid 512 covers B_*OUT_
  const int o = idx4 & (OUT_ - 1);
  float4 bv = *(const float4*)(pb + o);
  float4 r = bv;
  #pragma unroll
  for (int kz = 0; kz < NSPLIT; ++kz) {
    float4 a = *(const float4*)(part + (size_t)kz * B_ * OUT_ + idx4);
    r.x += a.x; r.y += a.y; r.z += a.z; r.w += a.w;
  }
  r.x = r.x > 0.f ? r.x : 0.f;
  r.y = r.y > 0.f ? r.y : 0.f;
  r.z = r.z > 0.f ? r.z : 0.f;
  r.w = r.w > 0.f ? r.w : 0.f;
  *(float4*)(out + idx4) = r;
}

// ---------------------------------------------------------------------------
extern "C" void kernel_launch(void* const* d_in, const int* in_sizes, int n_in,
                              void* d_out, int out_size, void* d_ws, size_t ws_size,
                              hipStream_t stream) {
  (void)in_sizes; (void)n_in; (void)out_size; (void)ws_size;
  const float* stat = (const float*)d_in[0];
  const float* asr  = (const float*)d_in[1];
  const float* mm   = (const float*)d_in[2];
  const float* w1   = (const float*)d_in[3];
  const float* b1   = (const float*)d_in[4];
  const float* w2   = (const float*)d_in[5];
  const float* b2   = (const float*)d_in[6];
  const float* tau  = (const float*)d_in[7];
  const float* emb  = (const float*)d_in[8];
  const float* pw   = (const float*)d_in[9];
  const float* pb   = (const float*)d_in[10];
  float* out = (float*)d_out;
  char* ws = (char*)d_ws;
  u16*   P    = (u16*)(ws);                 // 16,777,216 B
  u16*   Wn   = (u16*)(ws + 16777216);      //  2,555,904 B
  float* part = (float*)(ws + 19333120);    // 16,777,216 B

  producer_kernel<<<PRODUCER_BLOCKS, 256, 0, stream>>>(
      stat, w1, b1, w2, b2, tau, pw, emb, P, Wn);
  gemm_kernel<<<dim3(B_ / 64, OUT_ / 64, NSPLIT), 256, 0, stream>>>(
      asr, mm, P, Wn, part);
  combine_kernel<<<B_ * OUT_ / 1024, 256, 0, stream>>>(part, pb, out);
}